// Round 12
// baseline (494.778 us; speedup 1.0000x reference)
//
#include <hip/hip_runtime.h>
#include <hip/hip_cooperative_groups.h>
#include <hip/hip_bf16.h>

namespace cg = cooperative_groups;

#define F_OUT 64
#define NEG_SLOPE 0.2f
#define SOFT_EPS 1e-16f
#define BW 256          // nodes per bucket (i_local fits in 8 bits)
#define GRID_B 256      // cooperative grid blocks (trivially co-resident)

typedef short short8 __attribute__((ext_vector_type(8)));
typedef float floatx4 __attribute__((ext_vector_type(4)));
typedef unsigned short ushort4v __attribute__((ext_vector_type(4)));

__device__ __forceinline__ unsigned short f2bf_bits(float v) {
    __hip_bfloat16 hb = __float2bfloat16(v);
    return *(unsigned short*)&hb;
}
__device__ __forceinline__ float bf_bits2f(unsigned short u) {
    __hip_bfloat16 hb = *(__hip_bfloat16*)&u;
    return __bfloat162float(hb);
}
__device__ __forceinline__ float read_any(const void* src, int off, int bf) {
    return bf ? __bfloat162float(((const __hip_bfloat16*)src)[off])
              : ((const float*)src)[off];
}
__device__ __forceinline__ int get_idx(const void* ei, int i64, long long pos) {
    return i64 ? (int)((const long long*)ei)[pos] : ((const int*)ei)[pos];
}

// ---------------- cooperative CSR build: 7 kernels -> 1 ----------------
// Phases (grid.sync between): A count+weight-prep | B1 slice sums | B2 scan
// sums | B3 slice scan | C scatter | D per-bucket CSR.
struct BuildArgs {
    const unsigned* wbits; const unsigned* ebits;
    const void *w1, *as1, *ad1, *b1, *w2, *as2, *ad2, *b2;
    unsigned short *wt1, *wt2; float* vecs;
    int* flags; int* table; int* gsum; int* row_ptr;
    unsigned* staged; int* eidx;
    const void* ei;
    int E, N, total, NB, n1, n2, K1, CHsz;
};

__global__ void csr_build(BuildArgs a) {
    cg::grid_group grid = cg::this_grid();
    __shared__ int sm[520];           // [0..255] cnt/ldeg, [256..511] lcur, [512..515] wave sums, [516..517] flags
    int g = blockIdx.x;
    int tid = threadIdx.x;
    int lane = tid & 63, wv = tid >> 6;

    // per-block dtype detection (no cross-block dependency)
    if (tid < 64) {
        unsigned w = a.wbits[tid];
        unsigned e = (w >> 7) & 0xFFu;
        unsigned long long mb = __ballot(e >= 0x60u && e <= 0x7Eu);
        unsigned long long mz = __ballot(a.ebits[2 * tid + 1] == 0u);
        if (tid == 0) { sm[516] = (__popcll(mb) > 32); sm[517] = (__popcll(mz) > 32); }
    }
    __syncthreads();
    int bf = sm[516], i64 = sm[517];
    if (g == 0 && tid == 0) { a.flags[0] = bf; a.flags[1] = i64; }

    int base = g * a.CHsz;
    int lim = base + a.CHsz < a.total ? base + a.CHsz : a.total;

    // ---- phase A: per-chunk bucket histogram ----
    for (int k = tid; k < a.NB; k += 256) sm[k] = 0;
    __syncthreads();
    for (int t = base + tid; t < lim; t += 256) {
        int i = t < a.E ? get_idx(a.ei, i64, (long long)a.E + t) : t - a.E;
        atomicAdd(&sm[i >> 8], 1);
    }
    __syncthreads();
    for (int k = tid; k < a.NB; k += 256) a.table[k * GRID_B + g] = sm[k];
    // weight prep spread across the whole grid
    int wtotal = a.n1 + a.n2 + 384;
    for (int t = g * 256 + tid; t < wtotal; t += GRID_B * 256) {
        if (t < a.n1) {
            int n = t / a.K1, k = t - n * a.K1;
            a.wt1[t] = f2bf_bits(read_any(a.w1, k * F_OUT + n, bf));
        } else if (t < a.n1 + a.n2) {
            int u = t - a.n1;
            int n = u >> 6, k = u & 63;
            a.wt2[u] = f2bf_bits(read_any(a.w2, k * F_OUT + n, bf));
        } else {
            int u = t - a.n1 - a.n2;
            const void* srcp[6] = {a.as1, a.ad1, a.b1, a.as2, a.ad2, a.b2};
            a.vecs[u] = read_any(srcp[u >> 6], u & 63, bf);
        }
    }
    __threadfence();
    grid.sync();

    // ---- phase B1: per-slice sums (linear slice g = [g*NB, g*NB+NB)) ----
    {
        long long off = (long long)g * a.NB;
        int s = 0;
        for (int k = tid; k < a.NB; k += 256) s += a.table[off + k];
#pragma unroll
        for (int o = 1; o < 64; o <<= 1) s += __shfl_xor(s, o);
        if (lane == 0) sm[512 + wv] = s;
        __syncthreads();
        if (tid == 0) a.gsum[g] = sm[512] + sm[513] + sm[514] + sm[515];
    }
    __threadfence();
    grid.sync();

    // ---- phase B2: block 0 exclusive-scans gsum[0..GRID_B) ----
    if (g == 0) {
        int d = a.gsum[tid];
        int v = d;
#pragma unroll
        for (int o = 1; o < 64; o <<= 1) {
            int t2 = __shfl_up(v, o);
            if (lane >= o) v += t2;
        }
        __syncthreads();                 // sm[512..515] free for reuse
        if (lane == 63) sm[512 + wv] = v;
        __syncthreads();
        int woff = 0;
        for (int k = 0; k < wv; ++k) woff += sm[512 + k];
        a.gsum[tid] = v - d + woff;
        if (tid == 0) a.row_ptr[a.N] = a.total;
    }
    __threadfence();
    grid.sync();

    // ---- phase B3: in-place exclusive scan of slice g, offset by gsum[g] ----
    {
        long long off = (long long)g * a.NB;
        int carry = a.gsum[g];
        for (int bse = 0; bse < a.NB; bse += 256) {
            int idx = bse + tid;
            int d = (idx < a.NB) ? a.table[off + idx] : 0;
            int v = d;
#pragma unroll
            for (int o = 1; o < 64; o <<= 1) {
                int t2 = __shfl_up(v, o);
                if (lane >= o) v += t2;
            }
            if (lane == 63) sm[512 + wv] = v;
            __syncthreads();
            int woff = 0;
            for (int k = 0; k < wv; ++k) woff += sm[512 + k];
            int btot = sm[512] + sm[513] + sm[514] + sm[515];
            if (idx < a.NB) a.table[off + idx] = v - d + woff + carry;
            carry += btot;
            __syncthreads();
        }
    }
    __threadfence();
    grid.sync();

    // ---- phase C: scatter chunk g into bucket-major staging ----
    for (int k = tid; k < a.NB; k += 256) sm[k] = a.table[k * GRID_B + g];
    __syncthreads();
    for (int t = base + tid; t < lim; t += 256) {
        int i = t < a.E ? get_idx(a.ei, i64, (long long)a.E + t) : t - a.E;
        int j = t < a.E ? get_idx(a.ei, i64, t) : t - a.E;
        int pos = atomicAdd(&sm[i >> 8], 1);
        a.staged[pos] = ((unsigned)(i & 255) << 24) | (unsigned)j;
    }
    __threadfence();
    grid.sync();

    // ---- phase D: per-bucket CSR (row_ptr + in-segment eidx) ----
    for (int b = g; b < a.NB; b += GRID_B) {
        int seg_beg = a.table[b * GRID_B];
        int seg_end = (b + 1 < a.NB) ? a.table[(b + 1) * GRID_B] : a.total;
        sm[tid] = 0;
        __syncthreads();
        for (int p = seg_beg + tid; p < seg_end; p += 256)
            atomicAdd(&sm[a.staged[p] >> 24], 1);
        __syncthreads();
        int d = sm[tid];
        int v = d;
#pragma unroll
        for (int o = 1; o < 64; o <<= 1) {
            int t2 = __shfl_up(v, o);
            if (lane >= o) v += t2;
        }
        if (lane == 63) sm[512 + wv] = v;
        __syncthreads();
        int woff = 0;
        for (int k = 0; k < wv; ++k) woff += sm[512 + k];
        int excl = v - d + woff;
        int node = b * BW + tid;
        if (node < a.N) a.row_ptr[node] = seg_beg + excl;
        sm[256 + tid] = excl;
        __syncthreads();
        for (int p = seg_beg + tid; p < seg_end; p += 256) {
            unsigned pk = a.staged[p];
            int pos = atomicAdd(&sm[256 + (pk >> 24)], 1);
            a.eidx[seg_beg + pos] = (int)(pk & 0xFFFFFFu);
        }
        __syncthreads();
    }
}

// ---------- MFMA GEMM: h = x @ W (h stored bf16), fused attention dots ----------
template <int K>
__global__ void mfma_gemm(const void* __restrict__ xv, const unsigned short* __restrict__ Wt,
                          const float* __restrict__ att_s, const float* __restrict__ att_d,
                          unsigned short* __restrict__ h, float* __restrict__ a_s,
                          float* __restrict__ a_d, int N,
                          const int* __restrict__ flags, int in_mode) {
    int lane = threadIdx.x & 63;
    int m0 = (blockIdx.x * 4 + (threadIdx.x >> 6)) * 16;
    if (m0 >= N) return;
    int c = lane & 15, quad = lane >> 4;
    int arow = m0 + c;
    if (arow >= N) arow = N - 1;
    int bf = (in_mode == 2) ? flags[0] : in_mode;

    floatx4 acc0 = {0.f, 0.f, 0.f, 0.f};
    floatx4 acc1 = acc0, acc2 = acc0, acc3 = acc0;

    for (int kc = 0; kc < K; kc += 32) {
        int ka = kc + quad * 8;
        short8 a;
        if (bf) {
            a = *(const short8*)((const unsigned short*)xv + (size_t)arow * K + ka);
        } else {
            const float* xp = (const float*)xv + (size_t)arow * K + ka;
#pragma unroll
            for (int j = 0; j < 8; ++j) a[j] = (short)f2bf_bits(xp[j]);
        }
        short8 b0 = *(const short8*)(Wt + (size_t)(c)      * K + ka);
        short8 b1 = *(const short8*)(Wt + (size_t)(16 + c) * K + ka);
        short8 b2 = *(const short8*)(Wt + (size_t)(32 + c) * K + ka);
        short8 b3 = *(const short8*)(Wt + (size_t)(48 + c) * K + ka);
        acc0 = __builtin_amdgcn_mfma_f32_16x16x32_bf16(a, b0, acc0, 0, 0, 0);
        acc1 = __builtin_amdgcn_mfma_f32_16x16x32_bf16(a, b1, acc1, 0, 0, 0);
        acc2 = __builtin_amdgcn_mfma_f32_16x16x32_bf16(a, b2, acc2, 0, 0, 0);
        acc3 = __builtin_amdgcn_mfma_f32_16x16x32_bf16(a, b3, acc3, 0, 0, 0);
    }

    float as0 = att_s[c],      as1 = att_s[16 + c], as2 = att_s[32 + c], as3 = att_s[48 + c];
    float ad0 = att_d[c],      ad1 = att_d[16 + c], ad2 = att_d[32 + c], ad3 = att_d[48 + c];
#pragma unroll
    for (int reg = 0; reg < 4; ++reg) {
        int row = m0 + quad * 4 + reg;
        float vs = acc0[reg] * as0 + acc1[reg] * as1 + acc2[reg] * as2 + acc3[reg] * as3;
        float vd = acc0[reg] * ad0 + acc1[reg] * ad1 + acc2[reg] * ad2 + acc3[reg] * ad3;
#pragma unroll
        for (int off = 1; off < 16; off <<= 1) {
            vs += __shfl_xor(vs, off);
            vd += __shfl_xor(vd, off);
        }
        if (row < N) {
            if (c == 0) { a_s[row] = vs; a_d[row] = vd; }
            unsigned short* hr = h + (size_t)row * F_OUT + c;
            hr[0]  = f2bf_bits(acc0[reg]);
            hr[16] = f2bf_bits(acc1[reg]);
            hr[32] = f2bf_bits(acc2[reg]);
            hr[48] = f2bf_bits(acc3[reg]);
        }
    }
}

// ---------- fused softmax + gather + bias; 1 wave per node (quad-parallel rows) ----------
__global__ void node_gather(const int* __restrict__ row_ptr, const int* __restrict__ eidx,
                            const float* __restrict__ a_s, const float* __restrict__ a_d,
                            const unsigned short* __restrict__ h, const float* __restrict__ bias,
                            void* __restrict__ out, int N,
                            const int* __restrict__ flags, int mode) {
    int lane = threadIdx.x & 63;
    int i = blockIdx.x * 4 + (threadIdx.x >> 6);
    if (i >= N) return;
    int quad = lane >> 4, c = lane & 15;
    int beg = row_ptr[i];
    int end = row_ptr[i + 1];
    float ad = a_d[i];
    float se = 0.f;
    floatx4 acc[4];
#pragma unroll
    for (int k = 0; k < 4; ++k) acc[k] = (floatx4){0.f, 0.f, 0.f, 0.f};

    for (int p = beg; p < end; p += 64) {
        int tile = end - p; if (tile > 64) tile = 64;
        int jm = eidx[p + (lane < tile ? lane : tile - 1)];
        float wm = 0.f;
        if (lane < tile) {
            float e = a_s[jm] + ad;
            wm = __expf(e > 0.f ? e : NEG_SLOPE * e);
        }
        se += wm;
        for (int e = 0; e < tile; e += 16) {
#pragma unroll
            for (int k = 0; k < 4; ++k) {
                if (e + 4 * k < tile) {
                    int idx = e + 4 * k + quad;
                    int srcl = idx < tile ? idx : tile - 1;
                    int jk = __shfl(jm, srcl);
                    float wk = __shfl(wm, srcl);
                    if (idx >= tile) wk = 0.f;
                    ushort4v hv = *(const ushort4v*)(h + (size_t)jk * F_OUT + (c << 2));
                    acc[k][0] += wk * bf_bits2f(hv[0]);
                    acc[k][1] += wk * bf_bits2f(hv[1]);
                    acc[k][2] += wk * bf_bits2f(hv[2]);
                    acc[k][3] += wk * bf_bits2f(hv[3]);
                }
            }
        }
    }
#pragma unroll
    for (int off = 1; off < 64; off <<= 1) se += __shfl_xor(se, off);
    floatx4 A = (acc[0] + acc[1]) + (acc[2] + acc[3]);
#pragma unroll
    for (int m = 0; m < 4; ++m) {
        A[m] += __shfl_xor(A[m], 16);
        A[m] += __shfl_xor(A[m], 32);
    }
    if (quad == 0) {
        int col = c << 2;
        float inv = 1.f / (se + SOFT_EPS);
        float v0 = A[0] * inv + bias[col];
        float v1 = A[1] * inv + bias[col + 1];
        float v2 = A[2] * inv + bias[col + 2];
        float v3 = A[3] * inv + bias[col + 3];
        size_t o = (size_t)i * F_OUT + col;
        if (mode == 0) {
            ushort4v ov;
            ov[0] = f2bf_bits(v0 > 0.f ? v0 : 0.f);
            ov[1] = f2bf_bits(v1 > 0.f ? v1 : 0.f);
            ov[2] = f2bf_bits(v2 > 0.f ? v2 : 0.f);
            ov[3] = f2bf_bits(v3 > 0.f ? v3 : 0.f);
            *(ushort4v*)((unsigned short*)out + o) = ov;
        } else if (flags[0]) {
            ushort4v ov;
            ov[0] = f2bf_bits(v0); ov[1] = f2bf_bits(v1);
            ov[2] = f2bf_bits(v2); ov[3] = f2bf_bits(v3);
            *(ushort4v*)((unsigned short*)out + o) = ov;
        } else {
            floatx4 ov = {v0, v1, v2, v3};
            *(floatx4*)((float*)out + o) = ov;
        }
    }
}

extern "C" void kernel_launch(void* const* d_in, const int* in_sizes, int n_in,
                              void* d_out, int out_size, void* d_ws, size_t ws_size,
                              hipStream_t stream) {
    const void* x   = d_in[0];
    const void* ei  = d_in[1];
    const void* W1  = d_in[2];
    const void* as1 = d_in[3];
    const void* ad1 = d_in[4];
    const void* b1  = d_in[5];
    const void* W2  = d_in[6];
    const void* as2 = d_in[7];
    const void* ad2 = d_in[8];
    const void* b2  = d_in[9];

    int E  = in_sizes[1] / 2;          // 800000
    int n1 = in_sizes[2];              // 128*64
    int n2 = in_sizes[6];              // 64*64
    int K1 = n1 / F_OUT;               // 128
    int N  = in_sizes[0] / K1;         // 50000
    int total = E + N;
    int NB = (N + BW - 1) / BW;        // 196 buckets
    int M = NB * GRID_B;               // scan table size
    int CHsz = (total + GRID_B - 1) / GRID_B;

    size_t nf = (size_t)N * F_OUT;
    char* wsb = (char*)d_ws;
    unsigned short* h   = (unsigned short*)wsb;                 // nf bf16
    unsigned short* x1b = h + nf;                               // nf bf16
    unsigned short* wt1 = x1b + nf;                             // n1 bf16
    unsigned short* wt2 = wt1 + n1;                             // n2 bf16
    float* a_s  = (float*)(wt2 + n2 + ((n1 + n2) & 1));         // N f32 (align)
    float* a_d  = a_s + N;
    float* vecs = a_d + N;                                      // 384 f32
    float* cAs1 = vecs,       *cAd1 = vecs + 64,  *cB1 = vecs + 128;
    float* cAs2 = vecs + 192, *cAd2 = vecs + 256, *cB2 = vecs + 320;
    int* flags    = (int*)(vecs + 384);
    int* row_ptr  = flags + 8;            // N+1
    int* eidx     = row_ptr + N + 1;      // total
    unsigned* staged = (unsigned*)(eidx + total); // total
    int* table    = (int*)(staged + total);       // M
    int* gsum     = table + M;                    // GRID_B

    int blkGemm = (N + 63) / 64;       // 4 waves x 16 rows per block
    int blkNode = (N + 3) / 4;

    BuildArgs ba;
    ba.wbits = (const unsigned*)W1; ba.ebits = (const unsigned*)ei;
    ba.w1 = W1; ba.as1 = as1; ba.ad1 = ad1; ba.b1 = b1;
    ba.w2 = W2; ba.as2 = as2; ba.ad2 = ad2; ba.b2 = b2;
    ba.wt1 = wt1; ba.wt2 = wt2; ba.vecs = vecs;
    ba.flags = flags; ba.table = table; ba.gsum = gsum; ba.row_ptr = row_ptr;
    ba.staged = staged; ba.eidx = eidx; ba.ei = ei;
    ba.E = E; ba.N = N; ba.total = total; ba.NB = NB;
    ba.n1 = n1; ba.n2 = n2; ba.K1 = K1; ba.CHsz = CHsz;
    void* kp[] = {(void*)&ba};
    hipLaunchCooperativeKernel((const void*)csr_build, dim3(GRID_B), dim3(256),
                               kp, 0, stream);

    // ---- layer 1 ----
    mfma_gemm<128><<<blkGemm, 256, 0, stream>>>(x, wt1, cAs1, cAd1, h, a_s, a_d, N, flags, 2);
    node_gather<<<blkNode, 256, 0, stream>>>(row_ptr, eidx, a_s, a_d, h, cB1, x1b, N, flags, 0);

    // ---- layer 2 ----
    mfma_gemm<64><<<blkGemm, 256, 0, stream>>>(x1b, wt2, cAs2, cAd2, h, a_s, a_d, N, flags, 1);
    node_gather<<<blkNode, 256, 0, stream>>>(row_ptr, eidx, a_s, a_d, h, cB2, d_out, N, flags, 1);
}

// Round 13
// 213.033 us; speedup vs baseline: 2.3225x; 2.3225x over previous
//
#include <hip/hip_runtime.h>
#include <hip/hip_bf16.h>

#define F_OUT 64
#define NEG_SLOPE 0.2f
#define SOFT_EPS 1e-16f
#define BW 256          // nodes per bucket (i_local fits in 8 bits)
#define CH 8192         // edges per chunk
#define TH 512          // threads for count/scatter blocks

typedef short short8 __attribute__((ext_vector_type(8)));
typedef float floatx4 __attribute__((ext_vector_type(4)));
typedef unsigned short ushort4v __attribute__((ext_vector_type(4)));

__device__ __forceinline__ unsigned short f2bf_bits(float v) {
    __hip_bfloat16 hb = __float2bfloat16(v);
    return *(unsigned short*)&hb;
}
__device__ __forceinline__ float bf_bits2f(unsigned short u) {
    __hip_bfloat16 hb = *(__hip_bfloat16*)&u;
    return __bfloat162float(hb);
}
__device__ __forceinline__ float read_any(const void* src, int off, int bf) {
    return bf ? __bfloat162float(((const __hip_bfloat16*)src)[off])
              : ((const float*)src)[off];
}
__device__ __forceinline__ int get_idx(const void* ei, int i64, long long pos) {
    return i64 ? (int)((const long long*)ei)[pos] : ((const int*)ei)[pos];
}

// Per-block dtype detection (64-lane ballot on W1 low-halves / ei high words).
// Avoids cross-kernel flags dependency so independent kernels can merge.
__device__ __forceinline__ void detect_local(const unsigned* wbits, const unsigned* ebits,
                                             int* sm_bf, int* sm_i64) {
    if (threadIdx.x < 64) {
        unsigned w = wbits[threadIdx.x];
        unsigned e = (w >> 7) & 0xFFu;
        unsigned long long mb = __ballot(e >= 0x60u && e <= 0x7Eu);
        unsigned long long mz = __ballot(ebits[2 * threadIdx.x + 1] == 0u);
        if (threadIdx.x == 0) { *sm_bf = (__popcll(mb) > 32); *sm_i64 = (__popcll(mz) > 32); }
    }
    __syncthreads();
}

// ---------- D1: bucket_count (blocks 0..nchunks-1) ∥ prep weights (block nchunks) ----------
__global__ void count_prep(const void* __restrict__ ei, int* __restrict__ table,
                           const void* w1, const void* as1, const void* ad1, const void* b1,
                           const void* w2, const void* as2, const void* ad2, const void* b2,
                           unsigned short* __restrict__ wt1, unsigned short* __restrict__ wt2,
                           float* __restrict__ vecs, int* __restrict__ flags,
                           int E, int total, int NB, int nchunks, int n1, int n2, int K1) {
    __shared__ int cnt[1024];
    __shared__ int s_bf, s_i64;
    detect_local((const unsigned*)w1, (const unsigned*)ei, &s_bf, &s_i64);
    int bf = s_bf, i64 = s_i64;
    int g = blockIdx.x, tid = threadIdx.x;
    if (g == 0 && tid == 0) { flags[0] = bf; flags[1] = i64; }

    if (g < nchunks) {                     // ---- counting block ----
        for (int k = tid; k < NB; k += TH) cnt[k] = 0;
        __syncthreads();
        int base = g * CH;
        int lim = base + CH < total ? base + CH : total;
        for (int t = base + tid; t < lim; t += TH) {
            int i = t < E ? get_idx(ei, i64, (long long)E + t) : t - E;
            atomicAdd(&cnt[i >> 8], 1);
        }
        __syncthreads();
        for (int k = tid; k < NB; k += TH) table[k * nchunks + g] = cnt[k];
    } else {                               // ---- weight-prep block ----
        int wtotal = n1 + n2 + 384;
        for (int t = tid; t < wtotal; t += TH) {
            if (t < n1) {
                int n = t / K1, k = t - n * K1;
                wt1[t] = f2bf_bits(read_any(w1, k * F_OUT + n, bf));
            } else if (t < n1 + n2) {
                int u = t - n1;
                int n = u >> 6, k = u & 63;
                wt2[u] = f2bf_bits(read_any(w2, k * F_OUT + n, bf));
            } else {
                int u = t - n1 - n2;
                const void* srcp[6] = {as1, ad1, b1, as2, ad2, b2};
                vecs[u] = read_any(srcp[u >> 6], u & 63, bf);
            }
        }
    }
}

// ---------- MFMA GEMM body (shared by fused D2 and standalone layer 2) ----------
template <int K>
__device__ __forceinline__ void gemm_body(int blk, int tid,
                          const void* __restrict__ xv, const unsigned short* __restrict__ Wt,
                          const float* __restrict__ att_s, const float* __restrict__ att_d,
                          unsigned short* __restrict__ h, float* __restrict__ a_s,
                          float* __restrict__ a_d, int N, int bf) {
    int lane = tid & 63;
    int m0 = (blk * 4 + (tid >> 6)) * 16;
    if (m0 >= N) return;
    int c = lane & 15, quad = lane >> 4;
    int arow = m0 + c;
    if (arow >= N) arow = N - 1;

    floatx4 acc0 = {0.f, 0.f, 0.f, 0.f};
    floatx4 acc1 = acc0, acc2 = acc0, acc3 = acc0;

    for (int kc = 0; kc < K; kc += 32) {
        int ka = kc + quad * 8;
        short8 a;
        if (bf) {
            a = *(const short8*)((const unsigned short*)xv + (size_t)arow * K + ka);
        } else {
            const float* xp = (const float*)xv + (size_t)arow * K + ka;
#pragma unroll
            for (int j = 0; j < 8; ++j) a[j] = (short)f2bf_bits(xp[j]);
        }
        short8 b0 = *(const short8*)(Wt + (size_t)(c)      * K + ka);
        short8 b1 = *(const short8*)(Wt + (size_t)(16 + c) * K + ka);
        short8 b2 = *(const short8*)(Wt + (size_t)(32 + c) * K + ka);
        short8 b3 = *(const short8*)(Wt + (size_t)(48 + c) * K + ka);
        acc0 = __builtin_amdgcn_mfma_f32_16x16x32_bf16(a, b0, acc0, 0, 0, 0);
        acc1 = __builtin_amdgcn_mfma_f32_16x16x32_bf16(a, b1, acc1, 0, 0, 0);
        acc2 = __builtin_amdgcn_mfma_f32_16x16x32_bf16(a, b2, acc2, 0, 0, 0);
        acc3 = __builtin_amdgcn_mfma_f32_16x16x32_bf16(a, b3, acc3, 0, 0, 0);
    }

    float as0 = att_s[c],      as1 = att_s[16 + c], as2 = att_s[32 + c], as3 = att_s[48 + c];
    float ad0 = att_d[c],      ad1 = att_d[16 + c], ad2 = att_d[32 + c], ad3 = att_d[48 + c];
#pragma unroll
    for (int reg = 0; reg < 4; ++reg) {
        int row = m0 + quad * 4 + reg;
        float vs = acc0[reg] * as0 + acc1[reg] * as1 + acc2[reg] * as2 + acc3[reg] * as3;
        float vd = acc0[reg] * ad0 + acc1[reg] * ad1 + acc2[reg] * ad2 + acc3[reg] * ad3;
#pragma unroll
        for (int off = 1; off < 16; off <<= 1) {
            vs += __shfl_xor(vs, off);
            vd += __shfl_xor(vd, off);
        }
        if (row < N) {
            if (c == 0) { a_s[row] = vs; a_d[row] = vd; }
            unsigned short* hr = h + (size_t)row * F_OUT + c;
            hr[0]  = f2bf_bits(acc0[reg]);
            hr[16] = f2bf_bits(acc1[reg]);
            hr[32] = f2bf_bits(acc2[reg]);
            hr[48] = f2bf_bits(acc3[reg]);
        }
    }
}

// ---------- D2: gemm layer 1 (blocks < blkGemm) ∥ scan phase A (rest) ----------
__global__ void gemm1_scanA(const void* __restrict__ xv, const unsigned short* __restrict__ Wt,
                            const float* __restrict__ att_s, const float* __restrict__ att_d,
                            unsigned short* __restrict__ h, float* __restrict__ a_s,
                            float* __restrict__ a_d, int N, const int* __restrict__ flags,
                            const int* __restrict__ table, int* __restrict__ bsum,
                            int M, int blkGemm) {
    if ((int)blockIdx.x < blkGemm) {
        gemm_body<128>(blockIdx.x, threadIdx.x, xv, Wt, att_s, att_d, h, a_s, a_d, N, flags[0]);
        return;
    }
    int bid = blockIdx.x - blkGemm;
    int idx = bid * 1024 + threadIdx.x * 4;
    int s = 0;
#pragma unroll
    for (int j = 0; j < 4; ++j) { int k = idx + j; if (k < M) s += table[k]; }
#pragma unroll
    for (int off = 1; off < 64; off <<= 1) s += __shfl_xor(s, off);
    __shared__ int ws[4];
    int lane = threadIdx.x & 63, w = threadIdx.x >> 6;
    if (lane == 0) ws[w] = s;
    __syncthreads();
    if (threadIdx.x == 0) bsum[bid] = ws[0] + ws[1] + ws[2] + ws[3];
}

// ---------- D3: scan phase C with inlined phase B (local prefix of bsum) ----------
__global__ void scanC(int* __restrict__ data, const int* __restrict__ bsum, int n, int nbM,
                      int* __restrict__ extra, int extra_val) {
    __shared__ int sb[64];
    int tid = threadIdx.x;
    if (tid < 64) sb[tid] = (tid < nbM) ? bsum[tid] : 0;
    __syncthreads();
    int carry = 0;
    for (int k = 0; k < (int)blockIdx.x; ++k) carry += sb[k];   // nbM ~ 20
    if (blockIdx.x == 0 && tid == 0 && extra) *extra = extra_val;

    int idx = blockIdx.x * 1024 + tid * 4;
    int lane = tid & 63, w = tid >> 6;
    int d[4];
#pragma unroll
    for (int j = 0; j < 4; ++j) d[j] = (idx + j < n) ? data[idx + j] : 0;
    int tot = d[0] + d[1] + d[2] + d[3];
    int v = tot;
#pragma unroll
    for (int off = 1; off < 64; off <<= 1) {
        int t = __shfl_up(v, off);
        if (lane >= off) v += t;
    }
    __shared__ int wtot[4];
    if (lane == 63) wtot[w] = v;
    __syncthreads();
    int woff = 0;
    for (int k = 0; k < w; ++k) woff += wtot[k];
    int excl = v - tot + woff + carry;
    int o[4];
    o[0] = excl; o[1] = o[0] + d[0]; o[2] = o[1] + d[1]; o[3] = o[2] + d[2];
#pragma unroll
    for (int j = 0; j < 4; ++j)
        if (idx + j < n) data[idx + j] = o[j];
}

// ---------- D4: per-chunk scatter into bucket-major staging ----------
__global__ void stage_scatter(const void* __restrict__ ei, const int* __restrict__ table,
                              unsigned* __restrict__ staged, const unsigned* __restrict__ wbits,
                              int E, int total, int NB, int nchunks) {
    __shared__ int cur[1024];
    __shared__ int s_bf, s_i64;
    detect_local(wbits, (const unsigned*)ei, &s_bf, &s_i64);
    int i64 = s_i64;
    for (int k = threadIdx.x; k < NB; k += TH) cur[k] = table[k * nchunks + blockIdx.x];
    __syncthreads();
    int base = blockIdx.x * CH;
    int lim = base + CH < total ? base + CH : total;
    for (int t = base + threadIdx.x; t < lim; t += TH) {
        int i = t < E ? get_idx(ei, i64, (long long)E + t) : t - E;
        int j = t < E ? get_idx(ei, i64, t) : t - E;
        int pos = atomicAdd(&cur[i >> 8], 1);
        staged[pos] = ((unsigned)(i & 255) << 24) | (unsigned)j;
    }
}

// ---------- D5: per-bucket CSR (row_ptr + in-segment eidx) ----------
__global__ void bucket_csr(const unsigned* __restrict__ staged, const int* __restrict__ table,
                           int* __restrict__ row_ptr, int* __restrict__ eidx,
                           int N, int total, int NB, int nchunks) {
    __shared__ int ldeg[BW];
    __shared__ int lcur[BW];
    __shared__ int wtot[4];
    int b = blockIdx.x;
    int t = threadIdx.x;
    int seg_beg = table[b * nchunks];
    int seg_end = (b + 1 < NB) ? table[(b + 1) * nchunks] : total;
    ldeg[t] = 0;
    __syncthreads();
    for (int p = seg_beg + t; p < seg_end; p += 256)
        atomicAdd(&ldeg[staged[p] >> 24], 1);
    __syncthreads();
    int lane = t & 63, w = t >> 6;
    int d = ldeg[t];
    int v = d;
#pragma unroll
    for (int off = 1; off < 64; off <<= 1) {
        int u = __shfl_up(v, off);
        if (lane >= off) v += u;
    }
    if (lane == 63) wtot[w] = v;
    __syncthreads();
    int woff = 0;
    for (int k = 0; k < w; ++k) woff += wtot[k];
    int excl = v - d + woff;
    int node = b * BW + t;
    if (node < N) row_ptr[node] = seg_beg + excl;
    lcur[t] = excl;
    __syncthreads();
    for (int p = seg_beg + t; p < seg_end; p += 256) {
        unsigned pk = staged[p];
        int pos = atomicAdd(&lcur[pk >> 24], 1);
        eidx[seg_beg + pos] = (int)(pk & 0xFFFFFFu);
    }
}

// ---------- standalone layer-2 GEMM ----------
__global__ void mfma_gemm2(const void* __restrict__ xv, const unsigned short* __restrict__ Wt,
                           const float* __restrict__ att_s, const float* __restrict__ att_d,
                           unsigned short* __restrict__ h, float* __restrict__ a_s,
                           float* __restrict__ a_d, int N) {
    gemm_body<64>(blockIdx.x, threadIdx.x, xv, Wt, att_s, att_d, h, a_s, a_d, N, 1);
}

// ---------- fused softmax + gather + bias; 1 wave per node (quad-parallel rows) ----------
__global__ void node_gather(const int* __restrict__ row_ptr, const int* __restrict__ eidx,
                            const float* __restrict__ a_s, const float* __restrict__ a_d,
                            const unsigned short* __restrict__ h, const float* __restrict__ bias,
                            void* __restrict__ out, int N,
                            const int* __restrict__ flags, int mode) {
    int lane = threadIdx.x & 63;
    int i = blockIdx.x * 4 + (threadIdx.x >> 6);
    if (i >= N) return;
    int quad = lane >> 4, c = lane & 15;
    int beg = row_ptr[i];
    int end = row_ptr[i + 1];
    float ad = a_d[i];
    float se = 0.f;
    floatx4 acc[4];
#pragma unroll
    for (int k = 0; k < 4; ++k) acc[k] = (floatx4){0.f, 0.f, 0.f, 0.f};

    for (int p = beg; p < end; p += 64) {
        int tile = end - p; if (tile > 64) tile = 64;
        int jm = eidx[p + (lane < tile ? lane : tile - 1)];
        float wm = 0.f;
        if (lane < tile) {
            float e = a_s[jm] + ad;
            wm = __expf(e > 0.f ? e : NEG_SLOPE * e);
        }
        se += wm;
        for (int e = 0; e < tile; e += 16) {
#pragma unroll
            for (int k = 0; k < 4; ++k) {
                if (e + 4 * k < tile) {
                    int idx = e + 4 * k + quad;
                    int srcl = idx < tile ? idx : tile - 1;
                    int jk = __shfl(jm, srcl);
                    float wk = __shfl(wm, srcl);
                    if (idx >= tile) wk = 0.f;
                    ushort4v hv = *(const ushort4v*)(h + (size_t)jk * F_OUT + (c << 2));
                    acc[k][0] += wk * bf_bits2f(hv[0]);
                    acc[k][1] += wk * bf_bits2f(hv[1]);
                    acc[k][2] += wk * bf_bits2f(hv[2]);
                    acc[k][3] += wk * bf_bits2f(hv[3]);
                }
            }
        }
    }
#pragma unroll
    for (int off = 1; off < 64; off <<= 1) se += __shfl_xor(se, off);
    floatx4 A = (acc[0] + acc[1]) + (acc[2] + acc[3]);
#pragma unroll
    for (int m = 0; m < 4; ++m) {
        A[m] += __shfl_xor(A[m], 16);
        A[m] += __shfl_xor(A[m], 32);
    }
    if (quad == 0) {
        int col = c << 2;
        float inv = 1.f / (se + SOFT_EPS);
        float v0 = A[0] * inv + bias[col];
        float v1 = A[1] * inv + bias[col + 1];
        float v2 = A[2] * inv + bias[col + 2];
        float v3 = A[3] * inv + bias[col + 3];
        size_t o = (size_t)i * F_OUT + col;
        if (mode == 0) {
            ushort4v ov;
            ov[0] = f2bf_bits(v0 > 0.f ? v0 : 0.f);
            ov[1] = f2bf_bits(v1 > 0.f ? v1 : 0.f);
            ov[2] = f2bf_bits(v2 > 0.f ? v2 : 0.f);
            ov[3] = f2bf_bits(v3 > 0.f ? v3 : 0.f);
            *(ushort4v*)((unsigned short*)out + o) = ov;
        } else if (flags[0]) {
            ushort4v ov;
            ov[0] = f2bf_bits(v0); ov[1] = f2bf_bits(v1);
            ov[2] = f2bf_bits(v2); ov[3] = f2bf_bits(v3);
            *(ushort4v*)((unsigned short*)out + o) = ov;
        } else {
            floatx4 ov = {v0, v1, v2, v3};
            *(floatx4*)((float*)out + o) = ov;
        }
    }
}

extern "C" void kernel_launch(void* const* d_in, const int* in_sizes, int n_in,
                              void* d_out, int out_size, void* d_ws, size_t ws_size,
                              hipStream_t stream) {
    const void* x   = d_in[0];
    const void* ei  = d_in[1];
    const void* W1  = d_in[2];
    const void* as1 = d_in[3];
    const void* ad1 = d_in[4];
    const void* b1  = d_in[5];
    const void* W2  = d_in[6];
    const void* as2 = d_in[7];
    const void* ad2 = d_in[8];
    const void* b2  = d_in[9];

    int E  = in_sizes[1] / 2;          // 800000
    int n1 = in_sizes[2];              // 128*64
    int n2 = in_sizes[6];              // 64*64
    int K1 = n1 / F_OUT;               // 128
    int N  = in_sizes[0] / K1;         // 50000
    int total = E + N;
    int NB = (N + BW - 1) / BW;        // 196 buckets
    int nchunks = (total + CH - 1) / CH; // 104 chunks
    int M = NB * nchunks;              // 20384
    int nbM = (M + 1023) / 1024;       // 20

    size_t nf = (size_t)N * F_OUT;
    char* wsb = (char*)d_ws;
    unsigned short* h   = (unsigned short*)wsb;                 // nf bf16
    unsigned short* x1b = h + nf;                               // nf bf16
    unsigned short* wt1 = x1b + nf;                             // n1 bf16
    unsigned short* wt2 = wt1 + n1;                             // n2 bf16
    float* a_s  = (float*)(wt2 + n2 + ((n1 + n2) & 1));         // N f32 (align)
    float* a_d  = a_s + N;
    float* vecs = a_d + N;                                      // 384 f32
    float* cAs1 = vecs,       *cAd1 = vecs + 64,  *cB1 = vecs + 128;
    float* cAs2 = vecs + 192, *cAd2 = vecs + 256, *cB2 = vecs + 320;
    int* flags    = (int*)(vecs + 384);
    int* row_ptr  = flags + 8;            // N+1
    int* eidx     = row_ptr + N + 1;      // total
    unsigned* staged = (unsigned*)(eidx + total); // total
    int* table    = (int*)(staged + total);       // M
    int* bsum     = table + M;                    // nbM

    int blkGemm = (N + 63) / 64;       // 782: 4 waves x 16 rows per block
    int blkNode = (N + 3) / 4;

    // D1: bucket histogram ∥ weight prep
    count_prep<<<nchunks + 1, TH, 0, stream>>>(ei, table, W1, as1, ad1, b1,
                                               W2, as2, ad2, b2, wt1, wt2, vecs, flags,
                                               E, total, NB, nchunks, n1, n2, K1);
    // D2: layer-1 GEMM ∥ scan phase A
    gemm1_scanA<<<blkGemm + nbM, 256, 0, stream>>>(x, wt1, cAs1, cAd1, h, a_s, a_d, N,
                                                   flags, table, bsum, M, blkGemm);
    // D3: scan phase C (phase B inlined)
    scanC<<<nbM, 256, 0, stream>>>(table, bsum, M, nbM, row_ptr + N, total);
    // D4: scatter into bucket-major staging
    stage_scatter<<<nchunks, TH, 0, stream>>>(ei, table, staged, (const unsigned*)W1,
                                              E, total, NB, nchunks);
    // D5: per-bucket CSR
    bucket_csr<<<NB, 256, 0, stream>>>(staged, table, row_ptr, eidx, N, total, NB, nchunks);
    // D6: layer-1 gather
    node_gather<<<blkNode, 256, 0, stream>>>(row_ptr, eidx, a_s, a_d, h, cB1, x1b, N, flags, 0);
    // D7: layer-2 GEMM
    mfma_gemm2<<<blkGemm, 256, 0, stream>>>(x1b, wt2, cAs2, cAd2, h, a_s, a_d, N);
    // D8: layer-2 gather
    node_gather<<<blkNode, 256, 0, stream>>>(row_ptr, eidx, a_s, a_d, h, cB2, d_out, N, flags, 1);
}

// Round 14
// 207.074 us; speedup vs baseline: 2.3894x; 1.0288x over previous
//
#include <hip/hip_runtime.h>
#include <hip/hip_bf16.h>

#define F_OUT 64
#define NEG_SLOPE 0.2f
#define SOFT_EPS 1e-16f
#define BW 256          // nodes per bucket (i_local fits in 8 bits)
#define CH 8192         // edges per chunk
#define TH 512          // threads for count/scatter blocks

typedef short short8 __attribute__((ext_vector_type(8)));
typedef float floatx4 __attribute__((ext_vector_type(4)));
typedef unsigned short ushort4v __attribute__((ext_vector_type(4)));

__device__ __forceinline__ unsigned short f2bf_bits(float v) {
    __hip_bfloat16 hb = __float2bfloat16(v);
    return *(unsigned short*)&hb;
}
__device__ __forceinline__ float bf_bits2f(unsigned short u) {
    __hip_bfloat16 hb = *(__hip_bfloat16*)&u;
    return __bfloat162float(hb);
}
__device__ __forceinline__ float read_any(const void* src, int off, int bf) {
    return bf ? __bfloat162float(((const __hip_bfloat16*)src)[off])
              : ((const float*)src)[off];
}
__device__ __forceinline__ int get_idx(const void* ei, int i64, long long pos) {
    return i64 ? (int)((const long long*)ei)[pos] : ((const int*)ei)[pos];
}

// Per-block dtype detection (64-lane ballot on W1 low-halves / ei high words).
__device__ __forceinline__ void detect_local(const unsigned* wbits, const unsigned* ebits,
                                             int* sm_bf, int* sm_i64) {
    if (threadIdx.x < 64) {
        unsigned w = wbits[threadIdx.x];
        unsigned e = (w >> 7) & 0xFFu;
        unsigned long long mb = __ballot(e >= 0x60u && e <= 0x7Eu);
        unsigned long long mz = __ballot(ebits[2 * threadIdx.x + 1] == 0u);
        if (threadIdx.x == 0) { *sm_bf = (__popcll(mb) > 32); *sm_i64 = (__popcll(mz) > 32); }
    }
    __syncthreads();
}

// ---------- D1: bucket_count (blocks 0..nchunks-1) ∥ prep weights (block nchunks) ----------
__global__ void count_prep(const void* __restrict__ ei, int* __restrict__ table,
                           const void* w1, const void* as1, const void* ad1, const void* b1,
                           const void* w2, const void* as2, const void* ad2, const void* b2,
                           unsigned short* __restrict__ wt1, unsigned short* __restrict__ wt2,
                           float* __restrict__ vecs, int* __restrict__ flags,
                           int E, int total, int NB, int nchunks, int n1, int n2, int K1) {
    __shared__ int cnt[1024];
    __shared__ int s_bf, s_i64;
    detect_local((const unsigned*)w1, (const unsigned*)ei, &s_bf, &s_i64);
    int bf = s_bf, i64 = s_i64;
    int g = blockIdx.x, tid = threadIdx.x;
    if (g == 0 && tid == 0) { flags[0] = bf; flags[1] = i64; }

    if (g < nchunks) {                     // ---- counting block ----
        for (int k = tid; k < NB; k += TH) cnt[k] = 0;
        __syncthreads();
        int base = g * CH;
        int lim = base + CH < total ? base + CH : total;
        for (int t = base + tid; t < lim; t += TH) {
            int i = t < E ? get_idx(ei, i64, (long long)E + t) : t - E;
            atomicAdd(&cnt[i >> 8], 1);
        }
        __syncthreads();
        for (int k = tid; k < NB; k += TH) table[k * nchunks + g] = cnt[k];
    } else {                               // ---- weight-prep block ----
        int wtotal = n1 + n2 + 384;
        for (int t = tid; t < wtotal; t += TH) {
            if (t < n1) {
                int n = t / K1, k = t - n * K1;
                wt1[t] = f2bf_bits(read_any(w1, k * F_OUT + n, bf));
            } else if (t < n1 + n2) {
                int u = t - n1;
                int n = u >> 6, k = u & 63;
                wt2[u] = f2bf_bits(read_any(w2, k * F_OUT + n, bf));
            } else {
                int u = t - n1 - n2;
                const void* srcp[6] = {as1, ad1, b1, as2, ad2, b2};
                vecs[u] = read_any(srcp[u >> 6], u & 63, bf);
            }
        }
    }
}

// ---------- MFMA GEMM body (WAVES waves x 16 rows per block) ----------
template <int K, int WAVES>
__device__ __forceinline__ void gemm_body(int blk, int tid,
                          const void* __restrict__ xv, const unsigned short* __restrict__ Wt,
                          const float* __restrict__ att_s, const float* __restrict__ att_d,
                          unsigned short* __restrict__ h, float* __restrict__ a_s,
                          float* __restrict__ a_d, int N, int bf) {
    int lane = tid & 63;
    int m0 = (blk * WAVES + (tid >> 6)) * 16;
    if (m0 >= N) return;
    int c = lane & 15, quad = lane >> 4;
    int arow = m0 + c;
    if (arow >= N) arow = N - 1;

    floatx4 acc0 = {0.f, 0.f, 0.f, 0.f};
    floatx4 acc1 = acc0, acc2 = acc0, acc3 = acc0;

    for (int kc = 0; kc < K; kc += 32) {
        int ka = kc + quad * 8;
        short8 a;
        if (bf) {
            a = *(const short8*)((const unsigned short*)xv + (size_t)arow * K + ka);
        } else {
            const float* xp = (const float*)xv + (size_t)arow * K + ka;
#pragma unroll
            for (int j = 0; j < 8; ++j) a[j] = (short)f2bf_bits(xp[j]);
        }
        short8 b0 = *(const short8*)(Wt + (size_t)(c)      * K + ka);
        short8 b1 = *(const short8*)(Wt + (size_t)(16 + c) * K + ka);
        short8 b2 = *(const short8*)(Wt + (size_t)(32 + c) * K + ka);
        short8 b3 = *(const short8*)(Wt + (size_t)(48 + c) * K + ka);
        acc0 = __builtin_amdgcn_mfma_f32_16x16x32_bf16(a, b0, acc0, 0, 0, 0);
        acc1 = __builtin_amdgcn_mfma_f32_16x16x32_bf16(a, b1, acc1, 0, 0, 0);
        acc2 = __builtin_amdgcn_mfma_f32_16x16x32_bf16(a, b2, acc2, 0, 0, 0);
        acc3 = __builtin_amdgcn_mfma_f32_16x16x32_bf16(a, b3, acc3, 0, 0, 0);
    }

    float as0 = att_s[c],      as1 = att_s[16 + c], as2 = att_s[32 + c], as3 = att_s[48 + c];
    float ad0 = att_d[c],      ad1 = att_d[16 + c], ad2 = att_d[32 + c], ad3 = att_d[48 + c];
#pragma unroll
    for (int reg = 0; reg < 4; ++reg) {
        int row = m0 + quad * 4 + reg;
        float vs = acc0[reg] * as0 + acc1[reg] * as1 + acc2[reg] * as2 + acc3[reg] * as3;
        float vd = acc0[reg] * ad0 + acc1[reg] * ad1 + acc2[reg] * ad2 + acc3[reg] * ad3;
#pragma unroll
        for (int off = 1; off < 16; off <<= 1) {
            vs += __shfl_xor(vs, off);
            vd += __shfl_xor(vd, off);
        }
        if (row < N) {
            if (c == 0) { a_s[row] = vs; a_d[row] = vd; }
            unsigned short* hr = h + (size_t)row * F_OUT + c;
            hr[0]  = f2bf_bits(acc0[reg]);
            hr[16] = f2bf_bits(acc1[reg]);
            hr[32] = f2bf_bits(acc2[reg]);
            hr[48] = f2bf_bits(acc3[reg]);
        }
    }
}

// ---------- D2: scatter (blocks < nchunks, cursors self-computed from raw table)
//              ∥ layer-1 GEMM (remaining blocks, 8 waves x 16 rows) ----------
// cur[k] for chunk g = SB[k] (exclusive scan of bucket sums) + R[k] (bucket k's
// counts over chunks < g). Removes the global table-scan dispatches entirely.
__global__ void __launch_bounds__(TH)
scatter_gemm1(const void* __restrict__ ei, const int* __restrict__ table,
              unsigned* __restrict__ staged, int* __restrict__ segbeg,
              int* __restrict__ row_ptr, const void* __restrict__ xv,
              const unsigned short* __restrict__ Wt,
              const float* __restrict__ att_s, const float* __restrict__ att_d,
              unsigned short* __restrict__ h, float* __restrict__ a_s,
              float* __restrict__ a_d, const unsigned* __restrict__ wbits,
              int E, int total, int NB, int nchunks, int N) {
    __shared__ int s_bf, s_i64;
    detect_local(wbits, (const unsigned*)ei, &s_bf, &s_i64);
    int tid = threadIdx.x;
    if ((int)blockIdx.x >= nchunks) {      // ---- layer-1 GEMM role ----
        gemm_body<128, 8>(blockIdx.x - nchunks, tid, xv, Wt, att_s, att_d,
                          h, a_s, a_d, N, s_bf);
        return;
    }
    // ---- scatter role ----
    __shared__ int s_scan[TH];
    __shared__ int s_cur[1024];
    int g = blockIdx.x;
    int i64 = s_i64;
    int b0 = 0;
    if (tid < NB) {                        // NB (=196) <= TH
        const int* row = table + (size_t)tid * nchunks;
        int rsum = 0, rpart = 0;
        for (int c2 = 0; c2 < nchunks; ++c2) {
            int v = row[c2];
            rsum += v;
            rpart += (c2 < g) ? v : 0;
        }
        b0 = rsum;
        s_cur[tid] = rpart;
    }
    s_scan[tid] = (tid < NB) ? b0 : 0;
    __syncthreads();
    for (int off = 1; off < TH; off <<= 1) {   // Hillis-Steele inclusive scan
        int v = (tid >= off) ? s_scan[tid - off] : 0;
        __syncthreads();
        s_scan[tid] += v;
        __syncthreads();
    }
    if (tid < NB) {
        int excl = s_scan[tid] - b0;
        s_cur[tid] = excl + s_cur[tid];
        if (g == 0) segbeg[tid] = excl;
    }
    if (g == 0 && tid == 0) { segbeg[NB] = total; row_ptr[N] = total; }
    __syncthreads();
    int base = g * CH;
    int lim = base + CH < total ? base + CH : total;
    for (int t = base + tid; t < lim; t += TH) {
        int i = t < E ? get_idx(ei, i64, (long long)E + t) : t - E;
        int j = t < E ? get_idx(ei, i64, t) : t - E;
        int pos = atomicAdd(&s_cur[i >> 8], 1);
        staged[pos] = ((unsigned)(i & 255) << 24) | (unsigned)j;
    }
}

// ---------- D3: per-bucket CSR (row_ptr + in-segment eidx) ----------
__global__ void bucket_csr(const unsigned* __restrict__ staged, const int* __restrict__ segbeg,
                           int* __restrict__ row_ptr, int* __restrict__ eidx, int N) {
    __shared__ int ldeg[BW];
    __shared__ int lcur[BW];
    __shared__ int wtot[4];
    int b = blockIdx.x;
    int t = threadIdx.x;
    int seg_beg = segbeg[b];
    int seg_end = segbeg[b + 1];
    ldeg[t] = 0;
    __syncthreads();
    for (int p = seg_beg + t; p < seg_end; p += 256)
        atomicAdd(&ldeg[staged[p] >> 24], 1);
    __syncthreads();
    int lane = t & 63, w = t >> 6;
    int d = ldeg[t];
    int v = d;
#pragma unroll
    for (int off = 1; off < 64; off <<= 1) {
        int u = __shfl_up(v, off);
        if (lane >= off) v += u;
    }
    if (lane == 63) wtot[w] = v;
    __syncthreads();
    int woff = 0;
    for (int k = 0; k < w; ++k) woff += wtot[k];
    int excl = v - d + woff;
    int node = b * BW + t;
    if (node < N) row_ptr[node] = seg_beg + excl;
    lcur[t] = excl;
    __syncthreads();
    for (int p = seg_beg + t; p < seg_end; p += 256) {
        unsigned pk = staged[p];
        int pos = atomicAdd(&lcur[pk >> 24], 1);
        eidx[seg_beg + pos] = (int)(pk & 0xFFFFFFu);
    }
}

// ---------- D5: standalone layer-2 GEMM (4 waves x 16 rows) ----------
__global__ void mfma_gemm2(const void* __restrict__ xv, const unsigned short* __restrict__ Wt,
                           const float* __restrict__ att_s, const float* __restrict__ att_d,
                           unsigned short* __restrict__ h, float* __restrict__ a_s,
                           float* __restrict__ a_d, int N) {
    gemm_body<64, 4>(blockIdx.x, threadIdx.x, xv, Wt, att_s, att_d, h, a_s, a_d, N, 1);
}

// ---------- D4/D6: fused softmax + gather + bias; 1 wave per node ----------
__global__ void node_gather(const int* __restrict__ row_ptr, const int* __restrict__ eidx,
                            const float* __restrict__ a_s, const float* __restrict__ a_d,
                            const unsigned short* __restrict__ h, const float* __restrict__ bias,
                            void* __restrict__ out, int N,
                            const int* __restrict__ flags, int mode) {
    int lane = threadIdx.x & 63;
    int i = blockIdx.x * 4 + (threadIdx.x >> 6);
    if (i >= N) return;
    int quad = lane >> 4, c = lane & 15;
    int beg = row_ptr[i];
    int end = row_ptr[i + 1];
    float ad = a_d[i];
    float se = 0.f;
    floatx4 acc[4];
#pragma unroll
    for (int k = 0; k < 4; ++k) acc[k] = (floatx4){0.f, 0.f, 0.f, 0.f};

    for (int p = beg; p < end; p += 64) {
        int tile = end - p; if (tile > 64) tile = 64;
        int jm = eidx[p + (lane < tile ? lane : tile - 1)];
        float wm = 0.f;
        if (lane < tile) {
            float e = a_s[jm] + ad;
            wm = __expf(e > 0.f ? e : NEG_SLOPE * e);
        }
        se += wm;
        for (int e = 0; e < tile; e += 16) {
#pragma unroll
            for (int k = 0; k < 4; ++k) {
                if (e + 4 * k < tile) {
                    int idx = e + 4 * k + quad;
                    int srcl = idx < tile ? idx : tile - 1;
                    int jk = __shfl(jm, srcl);
                    float wk = __shfl(wm, srcl);
                    if (idx >= tile) wk = 0.f;
                    ushort4v hv = *(const ushort4v*)(h + (size_t)jk * F_OUT + (c << 2));
                    acc[k][0] += wk * bf_bits2f(hv[0]);
                    acc[k][1] += wk * bf_bits2f(hv[1]);
                    acc[k][2] += wk * bf_bits2f(hv[2]);
                    acc[k][3] += wk * bf_bits2f(hv[3]);
                }
            }
        }
    }
#pragma unroll
    for (int off = 1; off < 64; off <<= 1) se += __shfl_xor(se, off);
    floatx4 A = (acc[0] + acc[1]) + (acc[2] + acc[3]);
#pragma unroll
    for (int m = 0; m < 4; ++m) {
        A[m] += __shfl_xor(A[m], 16);
        A[m] += __shfl_xor(A[m], 32);
    }
    if (quad == 0) {
        int col = c << 2;
        float inv = 1.f / (se + SOFT_EPS);
        float v0 = A[0] * inv + bias[col];
        float v1 = A[1] * inv + bias[col + 1];
        float v2 = A[2] * inv + bias[col + 2];
        float v3 = A[3] * inv + bias[col + 3];
        size_t o = (size_t)i * F_OUT + col;
        if (mode == 0) {
            ushort4v ov;
            ov[0] = f2bf_bits(v0 > 0.f ? v0 : 0.f);
            ov[1] = f2bf_bits(v1 > 0.f ? v1 : 0.f);
            ov[2] = f2bf_bits(v2 > 0.f ? v2 : 0.f);
            ov[3] = f2bf_bits(v3 > 0.f ? v3 : 0.f);
            *(ushort4v*)((unsigned short*)out + o) = ov;
        } else if (flags[0]) {
            ushort4v ov;
            ov[0] = f2bf_bits(v0); ov[1] = f2bf_bits(v1);
            ov[2] = f2bf_bits(v2); ov[3] = f2bf_bits(v3);
            *(ushort4v*)((unsigned short*)out + o) = ov;
        } else {
            floatx4 ov = {v0, v1, v2, v3};
            *(floatx4*)((float*)out + o) = ov;
        }
    }
}

extern "C" void kernel_launch(void* const* d_in, const int* in_sizes, int n_in,
                              void* d_out, int out_size, void* d_ws, size_t ws_size,
                              hipStream_t stream) {
    const void* x   = d_in[0];
    const void* ei  = d_in[1];
    const void* W1  = d_in[2];
    const void* as1 = d_in[3];
    const void* ad1 = d_in[4];
    const void* b1  = d_in[5];
    const void* W2  = d_in[6];
    const void* as2 = d_in[7];
    const void* ad2 = d_in[8];
    const void* b2  = d_in[9];

    int E  = in_sizes[1] / 2;          // 800000
    int n1 = in_sizes[2];              // 128*64
    int n2 = in_sizes[6];              // 64*64
    int K1 = n1 / F_OUT;               // 128
    int N  = in_sizes[0] / K1;         // 50000
    int total = E + N;
    int NB = (N + BW - 1) / BW;        // 196 buckets (must be <= TH)
    int nchunks = (total + CH - 1) / CH; // 104 chunks
    int M = NB * nchunks;              // raw count table size

    size_t nf = (size_t)N * F_OUT;
    char* wsb = (char*)d_ws;
    unsigned short* h   = (unsigned short*)wsb;                 // nf bf16
    unsigned short* x1b = h + nf;                               // nf bf16
    unsigned short* wt1 = x1b + nf;                             // n1 bf16
    unsigned short* wt2 = wt1 + n1;                             // n2 bf16
    float* a_s  = (float*)(wt2 + n2 + ((n1 + n2) & 1));         // N f32 (align)
    float* a_d  = a_s + N;
    float* vecs = a_d + N;                                      // 384 f32
    float* cAs1 = vecs,       *cAd1 = vecs + 64,  *cB1 = vecs + 128;
    float* cAs2 = vecs + 192, *cAd2 = vecs + 256, *cB2 = vecs + 320;
    int* flags    = (int*)(vecs + 384);
    int* row_ptr  = flags + 8;            // N+1
    int* eidx     = row_ptr + N + 1;      // total
    unsigned* staged = (unsigned*)(eidx + total); // total
    int* table    = (int*)(staged + total);       // M
    int* segbeg   = table + M;                    // NB+1

    int blkG1 = (N + 127) / 128;       // 391: 8 waves x 16 rows per block
    int blkG2 = (N + 63) / 64;         // 782: 4 waves x 16 rows per block
    int blkNode = (N + 3) / 4;

    // D1: bucket histogram ∥ weight prep
    count_prep<<<nchunks + 1, TH, 0, stream>>>(ei, table, W1, as1, ad1, b1,
                                               W2, as2, ad2, b2, wt1, wt2, vecs, flags,
                                               E, total, NB, nchunks, n1, n2, K1);
    // D2: scatter (self-computed cursors) ∥ layer-1 GEMM
    scatter_gemm1<<<nchunks + blkG1, TH, 0, stream>>>(ei, table, staged, segbeg, row_ptr,
                                                      x, wt1, cAs1, cAd1, h, a_s, a_d,
                                                      (const unsigned*)W1,
                                                      E, total, NB, nchunks, N);
    // D3: per-bucket CSR
    bucket_csr<<<NB, 256, 0, stream>>>(staged, segbeg, row_ptr, eidx, N);
    // D4: layer-1 gather
    node_gather<<<blkNode, 256, 0, stream>>>(row_ptr, eidx, a_s, a_d, h, cB1, x1b, N, flags, 0);
    // D5: layer-2 GEMM
    mfma_gemm2<<<blkG2, 256, 0, stream>>>(x1b, wt2, cAs2, cAd2, h, a_s, a_d, N);
    // D6: layer-2 gather
    node_gather<<<blkNode, 256, 0, stream>>>(row_ptr, eidx, a_s, a_d, h, cB2, d_out, N, flags, 1);
}

// Round 15
// 206.538 us; speedup vs baseline: 2.3956x; 1.0026x over previous
//
#include <hip/hip_runtime.h>
#include <hip/hip_bf16.h>

#define F_OUT 64
#define NEG_SLOPE 0.2f
#define SOFT_EPS 1e-16f
#define BW 256          // nodes per bucket (i_local fits in 8 bits)
#define CH 8192         // edges per chunk
#define TH 512          // threads for count/scatter blocks

typedef short short8 __attribute__((ext_vector_type(8)));
typedef float floatx4 __attribute__((ext_vector_type(4)));
typedef unsigned short ushort4v __attribute__((ext_vector_type(4)));

__device__ __forceinline__ unsigned short f2bf_bits(float v) {
    __hip_bfloat16 hb = __float2bfloat16(v);
    return *(unsigned short*)&hb;
}
__device__ __forceinline__ float bf_bits2f(unsigned short u) {
    __hip_bfloat16 hb = *(__hip_bfloat16*)&u;
    return __bfloat162float(hb);
}
__device__ __forceinline__ float read_any(const void* src, int off, int bf) {
    return bf ? __bfloat162float(((const __hip_bfloat16*)src)[off])
              : ((const float*)src)[off];
}
__device__ __forceinline__ int get_idx(const void* ei, int i64, long long pos) {
    return i64 ? (int)((const long long*)ei)[pos] : ((const int*)ei)[pos];
}

// Per-block dtype detection (64-lane ballot on W1 low-halves / ei high words).
__device__ __forceinline__ void detect_local(const unsigned* wbits, const unsigned* ebits,
                                             int* sm_bf, int* sm_i64) {
    if (threadIdx.x < 64) {
        unsigned w = wbits[threadIdx.x];
        unsigned e = (w >> 7) & 0xFFu;
        unsigned long long mb = __ballot(e >= 0x60u && e <= 0x7Eu);
        unsigned long long mz = __ballot(ebits[2 * threadIdx.x + 1] == 0u);
        if (threadIdx.x == 0) { *sm_bf = (__popcll(mb) > 32); *sm_i64 = (__popcll(mz) > 32); }
    }
    __syncthreads();
}

// ---------- D1: bucket_count (blocks 0..nchunks-1) ∥ prep weights (block nchunks) ----------
__global__ void count_prep(const void* __restrict__ ei, int* __restrict__ table,
                           const void* w1, const void* as1, const void* ad1, const void* b1,
                           const void* w2, const void* as2, const void* ad2, const void* b2,
                           unsigned short* __restrict__ wt1, unsigned short* __restrict__ wt2,
                           float* __restrict__ vecs, int* __restrict__ flags,
                           int E, int total, int NB, int nchunks, int n1, int n2, int K1) {
    __shared__ int cnt[1024];
    __shared__ int s_bf, s_i64;
    detect_local((const unsigned*)w1, (const unsigned*)ei, &s_bf, &s_i64);
    int bf = s_bf, i64 = s_i64;
    int g = blockIdx.x, tid = threadIdx.x;
    if (g == 0 && tid == 0) { flags[0] = bf; flags[1] = i64; }

    if (g < nchunks) {                     // ---- counting block ----
        for (int k = tid; k < NB; k += TH) cnt[k] = 0;
        __syncthreads();
        int base = g * CH;
        int lim = base + CH < total ? base + CH : total;
        for (int t = base + tid; t < lim; t += TH) {
            int i = t < E ? get_idx(ei, i64, (long long)E + t) : t - E;
            atomicAdd(&cnt[i >> 8], 1);
        }
        __syncthreads();
        for (int k = tid; k < NB; k += TH) table[k * nchunks + g] = cnt[k];
    } else {                               // ---- weight-prep block ----
        int wtotal = n1 + n2 + 384;
        for (int t = tid; t < wtotal; t += TH) {
            if (t < n1) {
                int n = t / K1, k = t - n * K1;
                wt1[t] = f2bf_bits(read_any(w1, k * F_OUT + n, bf));
            } else if (t < n1 + n2) {
                int u = t - n1;
                int n = u >> 6, k = u & 63;
                wt2[u] = f2bf_bits(read_any(w2, k * F_OUT + n, bf));
            } else {
                int u = t - n1 - n2;
                const void* srcp[6] = {as1, ad1, b1, as2, ad2, b2};
                vecs[u] = read_any(srcp[u >> 6], u & 63, bf);
            }
        }
    }
}

// ---------- MFMA GEMM body (WAVES waves x 16 rows per block, global bf16/f32 A) ----------
template <int K, int WAVES>
__device__ __forceinline__ void gemm_body(int blk, int tid,
                          const void* __restrict__ xv, const unsigned short* __restrict__ Wt,
                          const float* __restrict__ att_s, const float* __restrict__ att_d,
                          unsigned short* __restrict__ h, float* __restrict__ a_s,
                          float* __restrict__ a_d, int N, int bf) {
    int lane = tid & 63;
    int m0 = (blk * WAVES + (tid >> 6)) * 16;
    if (m0 >= N) return;
    int c = lane & 15, quad = lane >> 4;
    int arow = m0 + c;
    if (arow >= N) arow = N - 1;

    floatx4 acc0 = {0.f, 0.f, 0.f, 0.f};
    floatx4 acc1 = acc0, acc2 = acc0, acc3 = acc0;

    for (int kc = 0; kc < K; kc += 32) {
        int ka = kc + quad * 8;
        short8 a;
        if (bf) {
            a = *(const short8*)((const unsigned short*)xv + (size_t)arow * K + ka);
        } else {
            const float* xp = (const float*)xv + (size_t)arow * K + ka;
#pragma unroll
            for (int j = 0; j < 8; ++j) a[j] = (short)f2bf_bits(xp[j]);
        }
        short8 b0 = *(const short8*)(Wt + (size_t)(c)      * K + ka);
        short8 b1 = *(const short8*)(Wt + (size_t)(16 + c) * K + ka);
        short8 b2 = *(const short8*)(Wt + (size_t)(32 + c) * K + ka);
        short8 b3 = *(const short8*)(Wt + (size_t)(48 + c) * K + ka);
        acc0 = __builtin_amdgcn_mfma_f32_16x16x32_bf16(a, b0, acc0, 0, 0, 0);
        acc1 = __builtin_amdgcn_mfma_f32_16x16x32_bf16(a, b1, acc1, 0, 0, 0);
        acc2 = __builtin_amdgcn_mfma_f32_16x16x32_bf16(a, b2, acc2, 0, 0, 0);
        acc3 = __builtin_amdgcn_mfma_f32_16x16x32_bf16(a, b3, acc3, 0, 0, 0);
    }

    float as0 = att_s[c],      as1 = att_s[16 + c], as2 = att_s[32 + c], as3 = att_s[48 + c];
    float ad0 = att_d[c],      ad1 = att_d[16 + c], ad2 = att_d[32 + c], ad3 = att_d[48 + c];
#pragma unroll
    for (int reg = 0; reg < 4; ++reg) {
        int row = m0 + quad * 4 + reg;
        float vs = acc0[reg] * as0 + acc1[reg] * as1 + acc2[reg] * as2 + acc3[reg] * as3;
        float vd = acc0[reg] * ad0 + acc1[reg] * ad1 + acc2[reg] * ad2 + acc3[reg] * ad3;
#pragma unroll
        for (int off = 1; off < 16; off <<= 1) {
            vs += __shfl_xor(vs, off);
            vd += __shfl_xor(vd, off);
        }
        if (row < N) {
            if (c == 0) { a_s[row] = vs; a_d[row] = vd; }
            unsigned short* hr = h + (size_t)row * F_OUT + c;
            hr[0]  = f2bf_bits(acc0[reg]);
            hr[16] = f2bf_bits(acc1[reg]);
            hr[32] = f2bf_bits(acc2[reg]);
            hr[48] = f2bf_bits(acc3[reg]);
        }
    }
}

// ---------- D2: scatter (blocks < nchunks, cursors self-computed from raw table)
//              ∥ layer-1 GEMM (remaining blocks, 8 waves x 16 rows) ----------
__global__ void __launch_bounds__(TH)
scatter_gemm1(const void* __restrict__ ei, const int* __restrict__ table,
              unsigned* __restrict__ staged, int* __restrict__ segbeg,
              int* __restrict__ row_ptr, const void* __restrict__ xv,
              const unsigned short* __restrict__ Wt,
              const float* __restrict__ att_s, const float* __restrict__ att_d,
              unsigned short* __restrict__ h, float* __restrict__ a_s,
              float* __restrict__ a_d, const unsigned* __restrict__ wbits,
              int E, int total, int NB, int nchunks, int N) {
    __shared__ int s_bf, s_i64;
    detect_local(wbits, (const unsigned*)ei, &s_bf, &s_i64);
    int tid = threadIdx.x;
    if ((int)blockIdx.x >= nchunks) {      // ---- layer-1 GEMM role ----
        gemm_body<128, 8>(blockIdx.x - nchunks, tid, xv, Wt, att_s, att_d,
                          h, a_s, a_d, N, s_bf);
        return;
    }
    // ---- scatter role ----
    __shared__ int s_scan[TH];
    __shared__ int s_cur[1024];
    int g = blockIdx.x;
    int i64 = s_i64;
    int b0 = 0;
    if (tid < NB) {                        // NB (=196) <= TH
        const int* row = table + (size_t)tid * nchunks;
        int rsum = 0, rpart = 0;
        for (int c2 = 0; c2 < nchunks; ++c2) {
            int v = row[c2];
            rsum += v;
            rpart += (c2 < g) ? v : 0;
        }
        b0 = rsum;
        s_cur[tid] = rpart;
    }
    s_scan[tid] = (tid < NB) ? b0 : 0;
    __syncthreads();
    for (int off = 1; off < TH; off <<= 1) {   // Hillis-Steele inclusive scan
        int v = (tid >= off) ? s_scan[tid - off] : 0;
        __syncthreads();
        s_scan[tid] += v;
        __syncthreads();
    }
    if (tid < NB) {
        int excl = s_scan[tid] - b0;
        s_cur[tid] = excl + s_cur[tid];
        if (g == 0) segbeg[tid] = excl;
    }
    if (g == 0 && tid == 0) { segbeg[NB] = total; row_ptr[N] = total; }
    __syncthreads();
    int base = g * CH;
    int lim = base + CH < total ? base + CH : total;
    for (int t = base + tid; t < lim; t += TH) {
        int i = t < E ? get_idx(ei, i64, (long long)E + t) : t - E;
        int j = t < E ? get_idx(ei, i64, t) : t - E;
        int pos = atomicAdd(&s_cur[i >> 8], 1);
        staged[pos] = ((unsigned)(i & 255) << 24) | (unsigned)j;
    }
}

// ---------- D3: per-bucket CSR (row_ptr + in-segment eidx) ----------
__global__ void bucket_csr(const unsigned* __restrict__ staged, const int* __restrict__ segbeg,
                           int* __restrict__ row_ptr, int* __restrict__ eidx, int N) {
    __shared__ int ldeg[BW];
    __shared__ int lcur[BW];
    __shared__ int wtot[4];
    int b = blockIdx.x;
    int t = threadIdx.x;
    int seg_beg = segbeg[b];
    int seg_end = segbeg[b + 1];
    ldeg[t] = 0;
    __syncthreads();
    for (int p = seg_beg + t; p < seg_end; p += 256)
        atomicAdd(&ldeg[staged[p] >> 24], 1);
    __syncthreads();
    int lane = t & 63, w = t >> 6;
    int d = ldeg[t];
    int v = d;
#pragma unroll
    for (int off = 1; off < 64; off <<= 1) {
        int u = __shfl_up(v, off);
        if (lane >= off) v += u;
    }
    if (lane == 63) wtot[w] = v;
    __syncthreads();
    int woff = 0;
    for (int k = 0; k < w; ++k) woff += wtot[k];
    int excl = v - d + woff;
    int node = b * BW + t;
    if (node < N) row_ptr[node] = seg_beg + excl;
    lcur[t] = excl;
    __syncthreads();
    for (int p = seg_beg + t; p < seg_end; p += 256) {
        unsigned pk = staged[p];
        int pos = atomicAdd(&lcur[pk >> 24], 1);
        eidx[seg_beg + pos] = (int)(pk & 0xFFFFFFu);
    }
}

// ---------- gather wave body (quad-parallel rows); returns per-lane partial state ----------
__device__ __forceinline__ void gather_node(int i, int lane, int quad, int c,
                                            const int* __restrict__ row_ptr,
                                            const int* __restrict__ eidx,
                                            const float* __restrict__ a_s,
                                            const float* __restrict__ a_d,
                                            const unsigned short* __restrict__ h,
                                            float* se_out, floatx4* A_out) {
    int beg = row_ptr[i];
    int end = row_ptr[i + 1];
    float ad = a_d[i];
    float se = 0.f;
    floatx4 acc[4];
#pragma unroll
    for (int k = 0; k < 4; ++k) acc[k] = (floatx4){0.f, 0.f, 0.f, 0.f};

    for (int p = beg; p < end; p += 64) {
        int tile = end - p; if (tile > 64) tile = 64;
        int jm = eidx[p + (lane < tile ? lane : tile - 1)];
        float wm = 0.f;
        if (lane < tile) {
            float e = a_s[jm] + ad;
            wm = __expf(e > 0.f ? e : NEG_SLOPE * e);
        }
        se += wm;
        for (int e = 0; e < tile; e += 16) {
#pragma unroll
            for (int k = 0; k < 4; ++k) {
                if (e + 4 * k < tile) {
                    int idx = e + 4 * k + quad;
                    int srcl = idx < tile ? idx : tile - 1;
                    int jk = __shfl(jm, srcl);
                    float wk = __shfl(wm, srcl);
                    if (idx >= tile) wk = 0.f;
                    ushort4v hv = *(const ushort4v*)(h + (size_t)jk * F_OUT + (c << 2));
                    acc[k][0] += wk * bf_bits2f(hv[0]);
                    acc[k][1] += wk * bf_bits2f(hv[1]);
                    acc[k][2] += wk * bf_bits2f(hv[2]);
                    acc[k][3] += wk * bf_bits2f(hv[3]);
                }
            }
        }
    }
#pragma unroll
    for (int off = 1; off < 64; off <<= 1) se += __shfl_xor(se, off);
    floatx4 A = (acc[0] + acc[1]) + (acc[2] + acc[3]);
#pragma unroll
    for (int m = 0; m < 4; ++m) {
        A[m] += __shfl_xor(A[m], 16);
        A[m] += __shfl_xor(A[m], 32);
    }
    *se_out = se;
    *A_out = A;
}

// ---------- D4: layer-1 gather (16 waves = 16 nodes) fused with layer-2 GEMM ----------
// Each wave gathers one node, writes its relu'd bf16 x1 row into a padded LDS
// tile (stride 72 shorts -> only 2-way bank aliasing, free). Wave 0 then runs
// the 16-row K=64 MFMA gemm from LDS, emitting layer-2 h2 / a_s2 / a_d2
// (separate buffers: other blocks still read layer-1 h/a_s/a_d concurrently).
#define XST 72
__global__ void __launch_bounds__(1024)
gather1_gemm2(const int* __restrict__ row_ptr, const int* __restrict__ eidx,
              const float* __restrict__ a_s, const float* __restrict__ a_d,
              const unsigned short* __restrict__ h, const float* __restrict__ bias,
              const unsigned short* __restrict__ Wt2,
              const float* __restrict__ att_s2, const float* __restrict__ att_d2,
              unsigned short* __restrict__ h2, float* __restrict__ a_s2,
              float* __restrict__ a_d2, int N) {
    __shared__ unsigned short x1t[16 * XST];
    int tid = threadIdx.x;
    int lane = tid & 63;
    int wv = tid >> 6;                    // 0..15 -> node row in tile
    int quad = lane >> 4, c = lane & 15;
    int i = blockIdx.x * 16 + wv;

    if (i < N) {
        float se; floatx4 A;
        gather_node(i, lane, quad, c, row_ptr, eidx, a_s, a_d, h, &se, &A);
        if (quad == 0) {
            int col = c << 2;
            float inv = 1.f / (se + SOFT_EPS);
            float v0 = A[0] * inv + bias[col];
            float v1 = A[1] * inv + bias[col + 1];
            float v2 = A[2] * inv + bias[col + 2];
            float v3 = A[3] * inv + bias[col + 3];
            ushort4v ov;
            ov[0] = f2bf_bits(v0 > 0.f ? v0 : 0.f);
            ov[1] = f2bf_bits(v1 > 0.f ? v1 : 0.f);
            ov[2] = f2bf_bits(v2 > 0.f ? v2 : 0.f);
            ov[3] = f2bf_bits(v3 > 0.f ? v3 : 0.f);
            *(ushort4v*)(x1t + wv * XST + col) = ov;
        }
    } else if (quad == 0) {
        *(ushort4v*)(x1t + wv * XST + (c << 2)) = (ushort4v){0, 0, 0, 0};
    }
    __syncthreads();

    if (wv == 0) {                        // ---- layer-2 GEMM for this 16-row tile ----
        int m0 = blockIdx.x * 16;
        floatx4 acc0 = {0.f, 0.f, 0.f, 0.f};
        floatx4 acc1 = acc0, acc2 = acc0, acc3 = acc0;
#pragma unroll
        for (int kc = 0; kc < 64; kc += 32) {
            int ka = kc + quad * 8;
            short8 a = *(const short8*)(x1t + c * XST + ka);
            short8 b0 = *(const short8*)(Wt2 + (size_t)(c)      * 64 + ka);
            short8 b1 = *(const short8*)(Wt2 + (size_t)(16 + c) * 64 + ka);
            short8 b2 = *(const short8*)(Wt2 + (size_t)(32 + c) * 64 + ka);
            short8 b3 = *(const short8*)(Wt2 + (size_t)(48 + c) * 64 + ka);
            acc0 = __builtin_amdgcn_mfma_f32_16x16x32_bf16(a, b0, acc0, 0, 0, 0);
            acc1 = __builtin_amdgcn_mfma_f32_16x16x32_bf16(a, b1, acc1, 0, 0, 0);
            acc2 = __builtin_amdgcn_mfma_f32_16x16x32_bf16(a, b2, acc2, 0, 0, 0);
            acc3 = __builtin_amdgcn_mfma_f32_16x16x32_bf16(a, b3, acc3, 0, 0, 0);
        }
        float as0 = att_s2[c],      as1 = att_s2[16 + c], as2 = att_s2[32 + c], as3 = att_s2[48 + c];
        float ad0 = att_d2[c],      ad1 = att_d2[16 + c], ad2 = att_d2[32 + c], ad3 = att_d2[48 + c];
#pragma unroll
        for (int reg = 0; reg < 4; ++reg) {
            int row = m0 + quad * 4 + reg;
            float vs = acc0[reg] * as0 + acc1[reg] * as1 + acc2[reg] * as2 + acc3[reg] * as3;
            float vd = acc0[reg] * ad0 + acc1[reg] * ad1 + acc2[reg] * ad2 + acc3[reg] * ad3;
#pragma unroll
            for (int off = 1; off < 16; off <<= 1) {
                vs += __shfl_xor(vs, off);
                vd += __shfl_xor(vd, off);
            }
            if (row < N) {
                if (c == 0) { a_s2[row] = vs; a_d2[row] = vd; }
                unsigned short* hr = h2 + (size_t)row * F_OUT + c;
                hr[0]  = f2bf_bits(acc0[reg]);
                hr[16] = f2bf_bits(acc1[reg]);
                hr[32] = f2bf_bits(acc2[reg]);
                hr[48] = f2bf_bits(acc3[reg]);
            }
        }
    }
}

// ---------- D5: layer-2 gather -> final output ----------
__global__ void node_gather_out(const int* __restrict__ row_ptr, const int* __restrict__ eidx,
                                const float* __restrict__ a_s, const float* __restrict__ a_d,
                                const unsigned short* __restrict__ h, const float* __restrict__ bias,
                                void* __restrict__ out, int N, const int* __restrict__ flags) {
    int lane = threadIdx.x & 63;
    int i = blockIdx.x * 4 + (threadIdx.x >> 6);
    if (i >= N) return;
    int quad = lane >> 4, c = lane & 15;
    float se; floatx4 A;
    gather_node(i, lane, quad, c, row_ptr, eidx, a_s, a_d, h, &se, &A);
    if (quad == 0) {
        int col = c << 2;
        float inv = 1.f / (se + SOFT_EPS);
        float v0 = A[0] * inv + bias[col];
        float v1 = A[1] * inv + bias[col + 1];
        float v2 = A[2] * inv + bias[col + 2];
        float v3 = A[3] * inv + bias[col + 3];
        size_t o = (size_t)i * F_OUT + col;
        if (flags[0]) {
            ushort4v ov;
            ov[0] = f2bf_bits(v0); ov[1] = f2bf_bits(v1);
            ov[2] = f2bf_bits(v2); ov[3] = f2bf_bits(v3);
            *(ushort4v*)((unsigned short*)out + o) = ov;
        } else {
            floatx4 ov = {v0, v1, v2, v3};
            *(floatx4*)((float*)out + o) = ov;
        }
    }
}

extern "C" void kernel_launch(void* const* d_in, const int* in_sizes, int n_in,
                              void* d_out, int out_size, void* d_ws, size_t ws_size,
                              hipStream_t stream) {
    const void* x   = d_in[0];
    const void* ei  = d_in[1];
    const void* W1  = d_in[2];
    const void* as1 = d_in[3];
    const void* ad1 = d_in[4];
    const void* b1  = d_in[5];
    const void* W2  = d_in[6];
    const void* as2 = d_in[7];
    const void* ad2 = d_in[8];
    const void* b2  = d_in[9];

    int E  = in_sizes[1] / 2;          // 800000
    int n1 = in_sizes[2];              // 128*64
    int n2 = in_sizes[6];              // 64*64
    int K1 = n1 / F_OUT;               // 128
    int N  = in_sizes[0] / K1;         // 50000
    int total = E + N;
    int NB = (N + BW - 1) / BW;        // 196 buckets (<= TH)
    int nchunks = (total + CH - 1) / CH; // 104 chunks
    int M = NB * nchunks;              // raw count table size

    size_t nf = (size_t)N * F_OUT;
    char* wsb = (char*)d_ws;
    unsigned short* h   = (unsigned short*)wsb;                 // nf bf16 (layer-1)
    unsigned short* h2  = h + nf;                               // nf bf16 (layer-2)
    unsigned short* wt1 = h2 + nf;                              // n1 bf16
    unsigned short* wt2 = wt1 + n1;                             // n2 bf16
    float* a_s  = (float*)(wt2 + n2 + ((n1 + n2) & 1));         // N f32
    float* a_d  = a_s + N;
    float* a_s2 = a_d + N;
    float* a_d2 = a_s2 + N;
    float* vecs = a_d2 + N;                                     // 384 f32
    float* cAs1 = vecs,       *cAd1 = vecs + 64,  *cB1 = vecs + 128;
    float* cAs2 = vecs + 192, *cAd2 = vecs + 256, *cB2 = vecs + 320;
    int* flags    = (int*)(vecs + 384);
    int* row_ptr  = flags + 8;            // N+1
    int* eidx     = row_ptr + N + 1;      // total
    unsigned* staged = (unsigned*)(eidx + total); // total
    int* table    = (int*)(staged + total);       // M
    int* segbeg   = table + M;                    // NB+1

    int blkG1 = (N + 127) / 128;       // 391: 8 waves x 16 rows per block
    int blkFuse = (N + 15) / 16;       // 3125: 16 waves = 16 nodes per block
    int blkNode = (N + 3) / 4;

    // D1: bucket histogram ∥ weight prep
    count_prep<<<nchunks + 1, TH, 0, stream>>>(ei, table, W1, as1, ad1, b1,
                                               W2, as2, ad2, b2, wt1, wt2, vecs, flags,
                                               E, total, NB, nchunks, n1, n2, K1);
    // D2: scatter (self-computed cursors) ∥ layer-1 GEMM
    scatter_gemm1<<<nchunks + blkG1, TH, 0, stream>>>(ei, table, staged, segbeg, row_ptr,
                                                      x, wt1, cAs1, cAd1, h, a_s, a_d,
                                                      (const unsigned*)W1,
                                                      E, total, NB, nchunks, N);
    // D3: per-bucket CSR
    bucket_csr<<<NB, 256, 0, stream>>>(staged, segbeg, row_ptr, eidx, N);
    // D4: layer-1 gather fused with layer-2 GEMM
    gather1_gemm2<<<blkFuse, 1024, 0, stream>>>(row_ptr, eidx, a_s, a_d, h, cB1,
                                                wt2, cAs2, cAd2, h2, a_s2, a_d2, N);
    // D5: layer-2 gather -> output
    node_gather_out<<<blkNode, 256, 0, stream>>>(row_ptr, eidx, a_s2, a_d2, h2, cB2,
                                                 d_out, N, flags);
}